// Round 4
// baseline (221.296 us; speedup 1.0000x reference)
//
#include <hip/hip_runtime.h>
#include <math.h>

#define T_DIM  1024
#define B_DIM  8
#define IN_D   512
#define NROWS  (T_DIM * B_DIM)      // 8192
#define EPSF   1e-8f

#define CHUNK  16
#define NCHUNK (T_DIM / CHUNK)      // 64

typedef float vfloat4 __attribute__((ext_vector_type(4)));

// ---- workspace layout (floats) ----
#define OFF_V    0
#define OFF_K    (OFF_V  + NROWS * 64)              // becomes w=k*decay in place
#define OFF_Z    (OFF_K  + NROWS * 64)              // alpha logits
#define OFF_P    (OFF_Z  + NROWS * 64)              // 64*8*4096 = 2097152

// kA: projections with inline weight transpose. 256 blocks x 256 thr; 32 rows/block, K-split-2.
__global__ __launch_bounds__(256) void kA_proj(
        const float* __restrict__ x,
        const float* __restrict__ Wv, const float* __restrict__ Wk, const float* __restrict__ Wa,
        const float* __restrict__ bv, const float* __restrict__ bk, const float* __restrict__ ba,
        float* __restrict__ V, float* __restrict__ Kb, float* __restrict__ Zb) {
    __shared__ float xs[2][32][32];     // [half][kk][row] transposed x
    __shared__ float wsm[2][32][192];   // [half][kk][c]   transposed weights
    const int tid  = threadIdx.x;
    const int h    = tid >> 7;          // K half
    const int t7   = tid & 127;
    const int rq   = t7 >> 4;           // row quad 0..7
    const int cq   = t7 & 15;           // col quad 0..15
    const int row0 = blockIdx.x * 32;

    float4 acc[4][3];
#pragma unroll
    for (int j = 0; j < 4; ++j)
#pragma unroll
        for (int m = 0; m < 3; ++m) acc[j][m] = make_float4(0.f, 0.f, 0.f, 0.f);

    for (int s = 0; s < 8; ++s) {       // K-slice of 32 per half per iter
        // stage x transposed: 512 float4 loads -> scalar transpose writes
#pragma unroll
        for (int q = 0; q < 2; ++q) {
            int idx = tid + q * 256;            // 0..511
            int hh = idx >> 8, r = idx & 31, f = (idx >> 5) & 7;
            float4 v4 = reinterpret_cast<const float4*>(x)[((row0 + r) * IN_D + hh * 256 + s * 32 + f * 4) >> 2];
            xs[hh][f * 4 + 0][r] = v4.x;
            xs[hh][f * 4 + 1][r] = v4.y;
            xs[hh][f * 4 + 2][r] = v4.z;
            xs[hh][f * 4 + 3][r] = v4.w;
        }
        // stage weights transposed: float4 along K from Wv/Wk/Wa -> scalar writes wsm[hh][kk][c]
        // 3072 float4 per s: idx -> c = idx%192, rest = idx/192 (hh = rest>>3, fq = rest&7)
#pragma unroll
        for (int q = 0; q < 12; ++q) {
            int idx = tid + q * 256;            // 0..3071
            int c = idx % 192;
            int rest = idx / 192;               // 0..15
            int hh = rest >> 3, fq = rest & 7;
            const float* Wsrc = (c < 64) ? Wv : ((c < 128) ? Wk : Wa);
            int ci = (c < 64) ? c : ((c < 128) ? c - 64 : c - 128);
            float4 v4 = *reinterpret_cast<const float4*>(Wsrc + ci * IN_D + hh * 256 + s * 32 + fq * 4);
            wsm[hh][fq * 4 + 0][c] = v4.x;
            wsm[hh][fq * 4 + 1][c] = v4.y;
            wsm[hh][fq * 4 + 2][c] = v4.z;
            wsm[hh][fq * 4 + 3][c] = v4.w;
        }
        __syncthreads();

#pragma unroll 4
        for (int kk = 0; kk < 32; ++kk) {
            float4 xv = *reinterpret_cast<const float4*>(&xs[h][kk][rq * 4]);
#pragma unroll
            for (int m = 0; m < 3; ++m) {
                float4 wq = *reinterpret_cast<const float4*>(&wsm[h][kk][m * 64 + cq * 4]);
#pragma unroll
                for (int j = 0; j < 4; ++j) {
                    float xx = (&xv.x)[j];
                    acc[j][m].x = fmaf(xx, wq.x, acc[j][m].x);
                    acc[j][m].y = fmaf(xx, wq.y, acc[j][m].y);
                    acc[j][m].z = fmaf(xx, wq.z, acc[j][m].z);
                    acc[j][m].w = fmaf(xx, wq.w, acc[j][m].w);
                }
            }
        }
        __syncthreads();
    }

    // cross-half reduce via LDS (reuse wsm; stride 52 floats to dodge bank conflicts)
    float* red = &wsm[0][0][0];
    if (h == 1) {
#pragma unroll
        for (int j = 0; j < 4; ++j)
#pragma unroll
            for (int m = 0; m < 3; ++m)
                *reinterpret_cast<float4*>(&red[t7 * 52 + (j * 3 + m) * 4]) = acc[j][m];
    }
    __syncthreads();
    if (h == 0) {
        float4 bv4 = *reinterpret_cast<const float4*>(&bv[cq * 4]);
        float4 bk4 = *reinterpret_cast<const float4*>(&bk[cq * 4]);
        float4 ba4 = *reinterpret_cast<const float4*>(&ba[cq * 4]);
#pragma unroll
        for (int j = 0; j < 4; ++j) {
            int row = row0 + rq * 4 + j;
            float4 o0 = *reinterpret_cast<const float4*>(&red[t7 * 52 + (j * 3 + 0) * 4]);
            float4 o1 = *reinterpret_cast<const float4*>(&red[t7 * 52 + (j * 3 + 1) * 4]);
            float4 o2 = *reinterpret_cast<const float4*>(&red[t7 * 52 + (j * 3 + 2) * 4]);
            float4 r0, r1, r2;
            r0.x = acc[j][0].x + o0.x + bv4.x; r0.y = acc[j][0].y + o0.y + bv4.y;
            r0.z = acc[j][0].z + o0.z + bv4.z; r0.w = acc[j][0].w + o0.w + bv4.w;
            r1.x = acc[j][1].x + o1.x + bk4.x; r1.y = acc[j][1].y + o1.y + bk4.y;
            r1.z = acc[j][1].z + o1.z + bk4.z; r1.w = acc[j][1].w + o1.w + bk4.w;
            r2.x = acc[j][2].x + o2.x + ba4.x; r2.y = acc[j][2].y + o2.y + ba4.y;
            r2.z = acc[j][2].z + o2.z + ba4.z; r2.w = acc[j][2].w + o2.w + ba4.w;
            *reinterpret_cast<float4*>(&V [row * 64 + cq * 4]) = r0;
            *reinterpret_cast<float4*>(&Kb[row * 64 + cq * 4]) = r1;
            *reinterpret_cast<float4*>(&Zb[row * 64 + cq * 4]) = r2;
        }
    }
}

// kB: fused log-sigmoid + full-T scan + decay apply. 512 blocks (one per channel) x 64 thr.
// lane owns t in [lane*16, lane*16+16); register prefix + wave64 shuffle scan.
__global__ __launch_bounds__(64) void kB_scan(const float* __restrict__ Z,
                                              float* __restrict__ Kb) {
    const int ch   = blockIdx.x;        // = b*64+n, matches row layout stride 512
    const int lane = threadIdx.x;
    const int t0   = lane * 16;
    float run[16];
    float acc = 0.f;
#pragma unroll
    for (int i = 0; i < 16; ++i) {
        float z = Z[(t0 + i) * 512 + ch];
        // log(max(sigmoid(z), 1e-8)) == max(min(z,0) - log1p(exp(-|z|)), log(1e-8))
        float l = fminf(z, 0.f) - __logf(1.f + __expf(-fabsf(z)));
        l = fmaxf(l, -18.4206807f);
        acc += l;
        run[i] = acc;
    }
    float incl = acc;
#pragma unroll
    for (int d = 1; d < 64; d <<= 1) {
        float tmp = __shfl_up(incl, d, 64);
        incl += (lane >= d) ? tmp : 0.f;
    }
    float excl = incl - acc;
    float Ltot = __shfl(incl, 63, 64);
    float inv  = 1.f / (__expf(Ltot) + EPSF);
#pragma unroll
    for (int i = 0; i < 16; ++i) {
        int idx = (t0 + i) * 512 + ch;
        Kb[idx] *= __expf(excl + run[i]) * inv;
    }
}

// kC: per-chunk partial outer sums P[c][b][d][n]. 512 blocks (b,c) x 256 thr.
__global__ __launch_bounds__(256) void kC_partial(const float* __restrict__ V,
                                                  const float* __restrict__ W,
                                                  float* __restrict__ P) {
    __shared__ float vs[CHUNK * 64];
    __shared__ float wsh[CHUNK * 64];
    int b = blockIdx.x & 7, cch = blockIdx.x >> 3;
    int tid = threadIdx.x;
    int dg = tid >> 4, n4 = tid & 15;
    {
        int il = tid >> 4, f = tid & 15;
        int row = (cch * CHUNK + il) * 8 + b;
        reinterpret_cast<float4*>(vs)[il * 16 + f]  = reinterpret_cast<const float4*>(V)[row * 16 + f];
        reinterpret_cast<float4*>(wsh)[il * 16 + f] = reinterpret_cast<const float4*>(W)[row * 16 + f];
    }
    __syncthreads();
    float4 acc[4];
#pragma unroll
    for (int q = 0; q < 4; ++q) acc[q] = make_float4(0.f, 0.f, 0.f, 0.f);

#pragma unroll
    for (int i = 0; i < CHUNK; ++i) {
        float4 wv = reinterpret_cast<const float4*>(wsh)[i * 16 + n4];
#pragma unroll
        for (int q = 0; q < 4; ++q) {
            float vd = vs[i * 64 + dg + 16 * q];
            acc[q].x = fmaf(vd, wv.x, acc[q].x);
            acc[q].y = fmaf(vd, wv.y, acc[q].y);
            acc[q].z = fmaf(vd, wv.z, acc[q].z);
            acc[q].w = fmaf(vd, wv.w, acc[q].w);
        }
    }
    float* Pp = P + (cch * 8 + b) * 4096;
#pragma unroll
    for (int q = 0; q < 4; ++q)
        *reinterpret_cast<float4*>(Pp + (dg + 16 * q) * 64 + 4 * n4) = acc[q];
}

// kD: exclusive prefix over 64 chunks — two-phase (burst-load all, then scan+store).
__global__ __launch_bounds__(256) void kD_prefix(float* __restrict__ P) {
    int gid = blockIdx.x * 256 + threadIdx.x;   // < 32768
    int b = gid >> 12, dn = gid & 4095;
    float vals[NCHUNK];
#pragma unroll
    for (int c = 0; c < NCHUNK; ++c) vals[c] = P[(c * 8 + b) * 4096 + dn];
    float run = 0.f;
#pragma unroll
    for (int c = 0; c < NCHUNK; ++c) { P[(c * 8 + b) * 4096 + dn] = run; run += vals[c]; }
}

// kE: main cumsum + streaming store (134 MB). 512 blocks (b,c) x 256 thr.
__global__ __launch_bounds__(256) void kE_main(const float* __restrict__ V,
                                               const float* __restrict__ W,
                                               const float* __restrict__ P,
                                               float* __restrict__ S) {
    __shared__ float vs[CHUNK * 64];
    __shared__ float wsh[CHUNK * 64];
    int b = blockIdx.x & 7, cch = blockIdx.x >> 3;
    int tid = threadIdx.x;
    int dg = tid >> 4, n4 = tid & 15;
    {
        int il = tid >> 4, f = tid & 15;
        int row = (cch * CHUNK + il) * 8 + b;
        reinterpret_cast<float4*>(vs)[il * 16 + f]  = reinterpret_cast<const float4*>(V)[row * 16 + f];
        reinterpret_cast<float4*>(wsh)[il * 16 + f] = reinterpret_cast<const float4*>(W)[row * 16 + f];
    }
    vfloat4 acc[4];
    const float* Pp = P + (cch * 8 + b) * 4096;
#pragma unroll
    for (int q = 0; q < 4; ++q)
        acc[q] = *reinterpret_cast<const vfloat4*>(Pp + (dg + 16 * q) * 64 + 4 * n4);
    __syncthreads();

#pragma unroll
    for (int i = 0; i < CHUNK; ++i) {
        float4 wv = reinterpret_cast<const float4*>(wsh)[i * 16 + n4];
        int t = cch * CHUNK + i;
        float* Sb = S + (size_t)t * 32768 + b * 4096;
#pragma unroll
        for (int q = 0; q < 4; ++q) {
            float vd = vs[i * 64 + dg + 16 * q];
            acc[q].x = fmaf(vd, wv.x, acc[q].x);
            acc[q].y = fmaf(vd, wv.y, acc[q].y);
            acc[q].z = fmaf(vd, wv.z, acc[q].z);
            acc[q].w = fmaf(vd, wv.w, acc[q].w);
            __builtin_nontemporal_store(acc[q],
                reinterpret_cast<vfloat4*>(Sb + (dg + 16 * q) * 64 + 4 * n4));
        }
    }
}

extern "C" void kernel_launch(void* const* d_in, const int* in_sizes, int n_in,
                              void* d_out, int out_size, void* d_ws, size_t ws_size,
                              hipStream_t stream) {
    const float* x  = (const float*)d_in[0];
    const float* Wv = (const float*)d_in[1];
    const float* bv = (const float*)d_in[2];
    const float* Wk = (const float*)d_in[3];
    const float* bk = (const float*)d_in[4];
    const float* Wa = (const float*)d_in[5];
    const float* ba = (const float*)d_in[6];
    float* S  = (float*)d_out;
    float* ws = (float*)d_ws;

    float* V   = ws + OFF_V;
    float* Kb  = ws + OFF_K;
    float* Zb  = ws + OFF_Z;
    float* P   = ws + OFF_P;

    kA_proj   <<<256, 256, 0, stream>>>(x, Wv, Wk, Wa, bv, bk, ba, V, Kb, Zb);
    kB_scan   <<<512,  64, 0, stream>>>(Zb, Kb);
    kC_partial<<<512, 256, 0, stream>>>(V, Kb, P);
    kD_prefix <<<128, 256, 0, stream>>>(P);
    kE_main   <<<512, 256, 0, stream>>>(V, Kb, P, S);
}